// Round 3
// baseline (285.010 us; speedup 1.0000x reference)
//
#include <hip/hip_runtime.h>
#include <hip/hip_bf16.h>
#include <hip/hip_fp16.h>

// SparseConvTranspose: gather-MFMA-scatter.
// Round 3: XCD-partitioned atomic accumulation. Messages are bucketed per
// (k, out-row slice of 50k rows); main kernel maps bucket -> XCD via
// blockIdx.x & 7 so every fp16-accum line is RMW'd from a single XCD
// (tests L2-resident-atomic model M vs memory-side model P). Waves are
// persistent over their bucket (B-frags loaded once, pipelined gathers).

using short8  = __attribute__((ext_vector_type(8))) short;
using floatx4 = __attribute__((ext_vector_type(4))) float;

constexpr int KOFF = 27;
constexpr int NIN  = 100000;
constexpr int NOUT = 400000;
constexpr int CIN  = 64;
constexpr int COUT = 32;
constexpr int MSGS = NIN;
constexpr int TILES = MSGS / 16;
constexpr int WPB   = 4;

constexpr int NBUCK = 8;                  // out-row slices (one per XCD)
constexpr int ROWS_PER_BUCK = NOUT / NBUCK;   // 50000
constexpr int CAP = 18432;                // per-(k,bucket) list capacity (mean 12500, sd ~105)
constexpr int BLOCKS_PER_BUCK = 8;        // persistent blocks per (k,bucket)

constexpr size_t ACC_BYTES   = (size_t)NOUT * COUT * 2;        // 25.6 MB
constexpr size_t FEATS_BYTES = (size_t)NIN * CIN * 2;          // 12.8 MB
constexpr size_t LIST_BYTES  = (size_t)KOFF * NBUCK * CAP * 4; // 15.9 MB
constexpr size_t CNT_BYTES   = 1024;                           // 27*8 ints, padded

__device__ __forceinline__ short f2bf(float f) {
    union { float f; unsigned u; } v; v.f = f;
    unsigned r = v.u + 0x7fff + ((v.u >> 16) & 1u);
    return (short)(r >> 16);
}

// ---------------- bucketing: per-(k, out-slice) message lists --------------
__global__ __launch_bounds__(256) void bucket_kernel(
    const int* __restrict__ out_map,
    int* __restrict__ lists,
    int* __restrict__ gcount)
{
    const int k    = blockIdx.y;
    const int tid  = threadIdx.x;
    const int mbase = blockIdx.x * 512;

    __shared__ int lbin[NBUCK];
    __shared__ int gbase[NBUCK];
    if (tid < NBUCK) lbin[tid] = 0;
    __syncthreads();

    int mm[2], bk[2], lpos[2], valid[2];
    #pragma unroll
    for (int j = 0; j < 2; ++j) {
        mm[j]    = mbase + j * 256 + tid;
        valid[j] = mm[j] < MSGS;
        if (valid[j]) {
            const int o = out_map[(long long)k * MSGS + mm[j]];
            bk[j]   = o / ROWS_PER_BUCK;          // 0..7
            lpos[j] = atomicAdd(&lbin[bk[j]], 1);
        }
    }
    __syncthreads();
    if (tid < NBUCK) gbase[tid] = atomicAdd(&gcount[k * NBUCK + tid], lbin[tid]);
    __syncthreads();
    #pragma unroll
    for (int j = 0; j < 2; ++j) {
        if (valid[j]) {
            const int p = gbase[bk[j]] + lpos[j];
            if (p < CAP) lists[((long long)(k * NBUCK + bk[j])) * CAP + p] = mm[j];
        }
    }
}

// ---------------- main: persistent, XCD-partitioned fp16 atomic accum ------
__global__ __launch_bounds__(256) void spconv_bucketed_kernel(
    const ushort* __restrict__ feats_bf,
    const float*  __restrict__ weight,
    const int*    __restrict__ in_map,
    const int*    __restrict__ out_map,
    const int*    __restrict__ lists,
    const int*    __restrict__ gcount,
    __half2*      __restrict__ accum)
{
    const int k    = blockIdx.y;
    const int b    = blockIdx.x & (NBUCK - 1);   // bucket == XCD heuristic
    const int chnk = blockIdx.x >> 3;            // 0..BLOCKS_PER_BUCK-1
    const int wave = threadIdx.x >> 6;
    const int lane = threadIdx.x & 63;
    const int col  = lane & 15;
    const int quad = lane >> 4;

    const int count = gcount[k * NBUCK + b];
    if (count <= 0) return;
    const int ntiles = (count + 15) >> 4;
    const int* list = lists + ((long long)(k * NBUCK + b)) * CAP;
    const long long kM = (long long)k * MSGS;

    // B fragments once per wave: bfr[s][t][j] = W[k][s*32+quad*8+j][2*col+t]
    const float* Wk = weight + k * (CIN * COUT);
    short8 bfr[2][2];
    #pragma unroll
    for (int s = 0; s < 2; ++s)
        #pragma unroll
        for (int t = 0; t < 2; ++t)
            #pragma unroll
            for (int j = 0; j < 8; ++j)
                bfr[s][t][j] = f2bf(Wk[(s * 32 + quad * 8 + j) * COUT + 2 * col + t]);

    const int wstride = BLOCKS_PER_BUCK * WPB;   // 32 waves per (k,bucket)
    for (int tile = chnk * WPB + wave; tile < ntiles; tile += wstride) {
        const int base = tile * 16;

        // A-row gather (lane col owns message base+col)
        int ecol = base + col;
        const bool vc = ecol < count;
        if (!vc) ecol = count - 1;
        const int mcol   = list[ecol];
        const int in_row = in_map[kM + mcol];

        const ushort* ar = feats_bf + (long long)in_row * CIN;
        short8 a0 = *(const short8*)(ar + quad * 8);
        short8 a1 = *(const short8*)(ar + 32 + quad * 8);
        if (!vc) { a0 = (short8)0; a1 = (short8)0; }  // dummy lanes add 0

        // out rows for the 4 C-rows this quad owns
        int orow[4];
        #pragma unroll
        for (int i = 0; i < 4; ++i) {
            int e = base + quad * 4 + i;
            if (e >= count) e = count - 1;
            orow[i] = out_map[kM + list[e]];
        }

        floatx4 acc0 = {0.f, 0.f, 0.f, 0.f};
        floatx4 acc1 = {0.f, 0.f, 0.f, 0.f};
        acc0 = __builtin_amdgcn_mfma_f32_16x16x32_bf16(a0, bfr[0][0], acc0, 0, 0, 0);
        acc1 = __builtin_amdgcn_mfma_f32_16x16x32_bf16(a0, bfr[0][1], acc1, 0, 0, 0);
        acc0 = __builtin_amdgcn_mfma_f32_16x16x32_bf16(a1, bfr[1][0], acc0, 0, 0, 0);
        acc1 = __builtin_amdgcn_mfma_f32_16x16x32_bf16(a1, bfr[1][1], acc1, 0, 0, 0);

        #pragma unroll
        for (int i = 0; i < 4; ++i) {
            __half2 h = __floats2half2_rn(acc0[i], acc1[i]);
            unsafeAtomicAdd(accum + (long long)orow[i] * 16 + col, h);
        }
    }
}

// ---------------- fallback (round-2): flat fp16-atomic kernel --------------
template<bool BF16F>
__global__ __launch_bounds__(256) void spconv_fp16acc_kernel(
    const float*  __restrict__ feats_f32,
    const ushort* __restrict__ feats_bf,
    const float*  __restrict__ weight,
    const int*    __restrict__ in_map,
    const int*    __restrict__ out_map,
    __half2*      __restrict__ accum)
{
    const int k    = blockIdx.y;
    const int wave = threadIdx.x >> 6;
    const int lane = threadIdx.x & 63;
    const int col  = lane & 15;
    const int quad = lane >> 4;
    const int tile = blockIdx.x * WPB + wave;
    if (tile >= TILES) return;
    const int m0 = tile * 16;
    const long long mapbase = (long long)k * MSGS;

    const int in_row = in_map[mapbase + m0 + col];
    int orow[4];
    #pragma unroll
    for (int i = 0; i < 4; ++i) orow[i] = out_map[mapbase + m0 + quad * 4 + i];

    const float* Wk = weight + k * (CIN * COUT);
    short8 bfr[2][2];
    #pragma unroll
    for (int s = 0; s < 2; ++s)
        #pragma unroll
        for (int t = 0; t < 2; ++t)
            #pragma unroll
            for (int j = 0; j < 8; ++j)
                bfr[s][t][j] = f2bf(Wk[(s * 32 + quad * 8 + j) * COUT + 2 * col + t]);

    short8 a0, a1;
    if (BF16F) {
        const ushort* ar = feats_bf + (long long)in_row * CIN;
        a0 = *(const short8*)(ar + quad * 8);
        a1 = *(const short8*)(ar + 32 + quad * 8);
    } else {
        const float* ar = feats_f32 + (long long)in_row * CIN + quad * 8;
        const float4* p0 = (const float4*)ar;
        const float4* p1 = (const float4*)(ar + 32);
        float4 l0 = p0[0], h0 = p0[1], l1 = p1[0], h1 = p1[1];
        a0[0]=f2bf(l0.x); a0[1]=f2bf(l0.y); a0[2]=f2bf(l0.z); a0[3]=f2bf(l0.w);
        a0[4]=f2bf(h0.x); a0[5]=f2bf(h0.y); a0[6]=f2bf(h0.z); a0[7]=f2bf(h0.w);
        a1[0]=f2bf(l1.x); a1[1]=f2bf(l1.y); a1[2]=f2bf(l1.z); a1[3]=f2bf(l1.w);
        a1[4]=f2bf(h1.x); a1[5]=f2bf(h1.y); a1[6]=f2bf(h1.z); a1[7]=f2bf(h1.w);
    }

    floatx4 acc0 = {0.f, 0.f, 0.f, 0.f};
    floatx4 acc1 = {0.f, 0.f, 0.f, 0.f};
    acc0 = __builtin_amdgcn_mfma_f32_16x16x32_bf16(a0, bfr[0][0], acc0, 0, 0, 0);
    acc1 = __builtin_amdgcn_mfma_f32_16x16x32_bf16(a0, bfr[0][1], acc1, 0, 0, 0);
    acc0 = __builtin_amdgcn_mfma_f32_16x16x32_bf16(a1, bfr[1][0], acc0, 0, 0, 0);
    acc1 = __builtin_amdgcn_mfma_f32_16x16x32_bf16(a1, bfr[1][1], acc1, 0, 0, 0);

    #pragma unroll
    for (int i = 0; i < 4; ++i) {
        __half2 h = __floats2half2_rn(acc0[i], acc1[i]);
        unsafeAtomicAdd(accum + (long long)orow[i] * 16 + col, h);
    }
}

// ---------------- last-resort fallback (round-1): f32 atomics to d_out -----
__global__ __launch_bounds__(256) void spconv_f32atomic_kernel(
    const float* __restrict__ feats,
    const float* __restrict__ weight,
    const int*   __restrict__ in_map,
    const int*   __restrict__ out_map,
    float*       __restrict__ out)
{
    const int k    = blockIdx.y;
    const int wave = threadIdx.x >> 6;
    const int lane = threadIdx.x & 63;
    const int col  = lane & 15;
    const int quad = lane >> 4;
    const int tile = blockIdx.x * WPB + wave;
    if (tile >= TILES) return;
    const int m0 = tile * 16;
    const long long mapbase = (long long)k * MSGS;

    const float* Wk = weight + k * (CIN * COUT);
    short8 bfr[2][2];
    #pragma unroll
    for (int s = 0; s < 2; ++s)
        #pragma unroll
        for (int t = 0; t < 2; ++t)
            #pragma unroll
            for (int j = 0; j < 8; ++j)
                bfr[s][t][j] = f2bf(Wk[(s * 32 + quad * 8 + j) * COUT + t * 16 + col]);

    const int in_row = in_map[mapbase + m0 + col];
    const float* arow = feats + (long long)in_row * CIN + quad * 8;

    floatx4 acc0 = {0.f, 0.f, 0.f, 0.f};
    floatx4 acc1 = {0.f, 0.f, 0.f, 0.f};
    #pragma unroll
    for (int s = 0; s < 2; ++s) {
        const float4* p = (const float4*)(arow + s * 32);
        float4 lo = p[0], hi = p[1];
        short8 a;
        a[0]=f2bf(lo.x); a[1]=f2bf(lo.y); a[2]=f2bf(lo.z); a[3]=f2bf(lo.w);
        a[4]=f2bf(hi.x); a[5]=f2bf(hi.y); a[6]=f2bf(hi.z); a[7]=f2bf(hi.w);
        acc0 = __builtin_amdgcn_mfma_f32_16x16x32_bf16(a, bfr[s][0], acc0, 0, 0, 0);
        acc1 = __builtin_amdgcn_mfma_f32_16x16x32_bf16(a, bfr[s][1], acc1, 0, 0, 0);
    }
    #pragma unroll
    for (int i = 0; i < 4; ++i) {
        const int orow = out_map[mapbase + m0 + quad * 4 + i];
        float* po = out + (long long)orow * COUT;
        atomicAdd(po + col,      acc0[i]);
        atomicAdd(po + col + 16, acc1[i]);
    }
}

// ---------------- feats f32 -> bf16 ----------------------------------------
__global__ __launch_bounds__(256) void feats_to_bf16_kernel(
    const float* __restrict__ f, ushort* __restrict__ b)
{
    const int t = blockIdx.x * blockDim.x + threadIdx.x;
    const float4* p = (const float4*)(f + (size_t)t * 8);
    float4 lo = p[0], hi = p[1];
    short8 v;
    v[0]=f2bf(lo.x); v[1]=f2bf(lo.y); v[2]=f2bf(lo.z); v[3]=f2bf(lo.w);
    v[4]=f2bf(hi.x); v[5]=f2bf(hi.y); v[6]=f2bf(hi.z); v[7]=f2bf(hi.w);
    *(short8*)(b + (size_t)t * 8) = v;
}

// ---------------- fp16 accum -> f32 out ------------------------------------
__global__ __launch_bounds__(256) void h2_to_f32_kernel(
    const __half2* __restrict__ acc, float* __restrict__ out)
{
    const int t = blockIdx.x * blockDim.x + threadIdx.x;
    const __half2* p = acc + (size_t)t * 4;
    float2 f0 = __half22float2(p[0]);
    float2 f1 = __half22float2(p[1]);
    float2 f2 = __half22float2(p[2]);
    float2 f3 = __half22float2(p[3]);
    float4* o = (float4*)out + (size_t)t * 2;
    o[0] = make_float4(f0.x, f0.y, f1.x, f1.y);
    o[1] = make_float4(f2.x, f2.y, f3.x, f3.y);
}

extern "C" void kernel_launch(void* const* d_in, const int* in_sizes, int n_in,
                              void* d_out, int out_size, void* d_ws, size_t ws_size,
                              hipStream_t stream) {
    const float* feats   = (const float*)d_in[0];
    const float* weight  = (const float*)d_in[1];
    const int*   in_map  = (const int*)d_in[2];
    const int*   out_map = (const int*)d_in[3];
    float*       out     = (float*)d_out;

    if (ws_size >= ACC_BYTES + FEATS_BYTES + LIST_BYTES + CNT_BYTES) {
        __half2* accum    = (__half2*)d_ws;
        ushort*  feats_bf = (ushort*)((char*)d_ws + ACC_BYTES);
        int*     lists    = (int*)((char*)d_ws + ACC_BYTES + FEATS_BYTES);
        int*     gcount   = (int*)((char*)d_ws + ACC_BYTES + FEATS_BYTES + LIST_BYTES);

        hipMemsetAsync(accum, 0, ACC_BYTES, stream);
        hipMemsetAsync(gcount, 0, CNT_BYTES, stream);
        feats_to_bf16_kernel<<<(NIN * CIN / 8) / 256, 256, 0, stream>>>(feats, feats_bf);
        bucket_kernel<<<dim3((MSGS + 511) / 512, KOFF), 256, 0, stream>>>(
            out_map, lists, gcount);
        spconv_bucketed_kernel<<<dim3(NBUCK * BLOCKS_PER_BUCK, KOFF), 256, 0, stream>>>(
            feats_bf, weight, in_map, out_map, lists, gcount, accum);
        h2_to_f32_kernel<<<(NOUT * 16 / 4) / 256, 256, 0, stream>>>(accum, out);
    } else if (ws_size >= ACC_BYTES + FEATS_BYTES) {
        __half2* accum    = (__half2*)d_ws;
        ushort*  feats_bf = (ushort*)((char*)d_ws + ACC_BYTES);
        hipMemsetAsync(accum, 0, ACC_BYTES, stream);
        feats_to_bf16_kernel<<<(NIN * CIN / 8) / 256, 256, 0, stream>>>(feats, feats_bf);
        spconv_fp16acc_kernel<true><<<dim3((TILES + WPB - 1) / WPB, KOFF), 256, 0, stream>>>(
            feats, feats_bf, weight, in_map, out_map, accum);
        h2_to_f32_kernel<<<(NOUT * 16 / 4) / 256, 256, 0, stream>>>(accum, out);
    } else if (ws_size >= ACC_BYTES) {
        __half2* accum = (__half2*)d_ws;
        hipMemsetAsync(accum, 0, ACC_BYTES, stream);
        spconv_fp16acc_kernel<false><<<dim3((TILES + WPB - 1) / WPB, KOFF), 256, 0, stream>>>(
            feats, nullptr, weight, in_map, out_map, accum);
        h2_to_f32_kernel<<<(NOUT * 16 / 4) / 256, 256, 0, stream>>>(accum, out);
    } else {
        hipMemsetAsync(d_out, 0, (size_t)out_size * sizeof(float), stream);
        spconv_f32atomic_kernel<<<dim3((TILES + WPB - 1) / WPB, KOFF), 256, 0, stream>>>(
            feats, weight, in_map, out_map, out);
    }
}

// Round 4
// 260.063 us; speedup vs baseline: 1.0959x; 1.0959x over previous
//
#include <hip/hip_runtime.h>
#include <hip/hip_bf16.h>
#include <hip/hip_fp16.h>

// SparseConvTranspose: gather-MFMA-scatter.
// Round 4: flat message order (coalesced maps), persistent waves, 3-stage
// software pipeline (maps[t+2] / feats[t+1] prefetch while computing t),
// fp16 packed memory-side atomics (Model P: location-independent, so no
// bucketing). Prep kernel fuses accum-zeroing with feats f32->bf16 convert.

using short8  = __attribute__((ext_vector_type(8))) short;
using floatx4 = __attribute__((ext_vector_type(4))) float;

constexpr int KOFF = 27;
constexpr int NIN  = 100000;
constexpr int NOUT = 400000;
constexpr int CIN  = 64;
constexpr int COUT = 32;
constexpr int MSGS = NIN;
constexpr int TILES = MSGS / 16;          // 6250
constexpr int WPB   = 4;                  // waves per block
constexpr int BLK_PER_K = 64;             // persistent blocks per kernel offset
constexpr int WSTRIDE = BLK_PER_K * WPB;  // 256 waves per k -> ~24 tiles/wave

constexpr size_t ACC_BYTES   = (size_t)NOUT * COUT * 2;   // 25.6 MB fp16 accum
constexpr size_t FEATS_BYTES = (size_t)NIN * CIN * 2;     // 12.8 MB bf16 feats

constexpr int CVT_BLOCKS  = (NIN * CIN / 8) / 256;        // 3125
constexpr int ZERO_BLOCKS = (int)(ACC_BYTES / 16) / 256;  // 6250

__device__ __forceinline__ short f2bf(float f) {
    union { float f; unsigned u; } v; v.f = f;
    unsigned r = v.u + 0x7fff + ((v.u >> 16) & 1u);
    return (short)(r >> 16);
}

// ---------------- prep: feats f32->bf16 convert + accum zero ---------------
__global__ __launch_bounds__(256) void prep_kernel(
    const float* __restrict__ f, ushort* __restrict__ b, float4* __restrict__ accz)
{
    if (blockIdx.x < CVT_BLOCKS) {
        const int t = blockIdx.x * 256 + threadIdx.x;
        const float4* p = (const float4*)(f + (size_t)t * 8);
        float4 lo = p[0], hi = p[1];
        short8 v;
        v[0]=f2bf(lo.x); v[1]=f2bf(lo.y); v[2]=f2bf(lo.z); v[3]=f2bf(lo.w);
        v[4]=f2bf(hi.x); v[5]=f2bf(hi.y); v[6]=f2bf(hi.z); v[7]=f2bf(hi.w);
        *(short8*)(b + (size_t)t * 8) = v;
    } else {
        const int t = (blockIdx.x - CVT_BLOCKS) * 256 + threadIdx.x;
        accz[t] = make_float4(0.f, 0.f, 0.f, 0.f);
    }
}

// ---------------- main: pipelined gather-MFMA-scatter ----------------------
__global__ __launch_bounds__(256) void spconv_pipe_kernel(
    const ushort* __restrict__ feats_bf,
    const float*  __restrict__ weight,
    const int*    __restrict__ in_map,
    const int*    __restrict__ out_map,
    __half2*      __restrict__ accum)
{
    const int k    = blockIdx.y;
    const int wave = threadIdx.x >> 6;
    const int lane = threadIdx.x & 63;
    const int col  = lane & 15;
    const int quad = lane >> 4;
    const long long kM = (long long)k * MSGS;

    // B fragments once per wave: bfr[s][t][j] = W[k][s*32+quad*8+j][2*col+t]
    // (frag t holds out-column 2*col+t -> each lane owns an adjacent col pair)
    const float* Wk = weight + k * (CIN * COUT);
    short8 bfr[2][2];
    #pragma unroll
    for (int s = 0; s < 2; ++s)
        #pragma unroll
        for (int t = 0; t < 2; ++t)
            #pragma unroll
            for (int j = 0; j < 8; ++j)
                bfr[s][t][j] = f2bf(Wk[(s * 32 + quad * 8 + j) * COUT + 2 * col + t]);

    #define LOAD_MAPS(t, inr, orow)                                   \
        {                                                             \
            const int tt = ((t) < TILES) ? (t) : (TILES - 1);         \
            const long long mb = kM + (long long)tt * 16;             \
            inr = in_map[mb + col];                                   \
            _Pragma("unroll")                                         \
            for (int i = 0; i < 4; ++i) orow[i] = out_map[mb + quad * 4 + i]; \
        }

    #define LOAD_FEATS(inr, a0, a1)                                   \
        {                                                             \
            const ushort* ar = feats_bf + (long long)(inr) * CIN;     \
            a0 = *(const short8*)(ar + quad * 8);                     \
            a1 = *(const short8*)(ar + 32 + quad * 8);                \
        }

    const int t0 = blockIdx.x * WPB + wave;

    int inrA, orowA[4];  LOAD_MAPS(t0,            inrA, orowA);
    int inrB, orowB[4];  LOAD_MAPS(t0 + WSTRIDE,  inrB, orowB);
    short8 a0A, a1A;     LOAD_FEATS(inrA, a0A, a1A);

    for (int t = t0; t < TILES; t += WSTRIDE) {
        // stage 3: maps for t+2*WSTRIDE
        int inrC, orowC[4];
        LOAD_MAPS(t + 2 * WSTRIDE, inrC, orowC);
        // stage 2: feats for t+WSTRIDE (consumes inrB)
        short8 a0B, a1B;
        LOAD_FEATS(inrB, a0B, a1B);

        // stage 1: compute + scatter current tile (consumes a0A/a1A/orowA)
        floatx4 acc0 = {0.f, 0.f, 0.f, 0.f};
        floatx4 acc1 = {0.f, 0.f, 0.f, 0.f};
        acc0 = __builtin_amdgcn_mfma_f32_16x16x32_bf16(a0A, bfr[0][0], acc0, 0, 0, 0);
        acc1 = __builtin_amdgcn_mfma_f32_16x16x32_bf16(a0A, bfr[0][1], acc1, 0, 0, 0);
        acc0 = __builtin_amdgcn_mfma_f32_16x16x32_bf16(a1A, bfr[1][0], acc0, 0, 0, 0);
        acc1 = __builtin_amdgcn_mfma_f32_16x16x32_bf16(a1A, bfr[1][1], acc1, 0, 0, 0);

        #pragma unroll
        for (int i = 0; i < 4; ++i) {
            __half2 h = __floats2half2_rn(acc0[i], acc1[i]);
            unsafeAtomicAdd(accum + (long long)orowA[i] * 16 + col, h);
        }

        // rotate pipeline registers
        inrA = inrB; a0A = a0B; a1A = a1B;
        inrB = inrC;
        #pragma unroll
        for (int i = 0; i < 4; ++i) { orowA[i] = orowB[i]; orowB[i] = orowC[i]; }
    }
    #undef LOAD_MAPS
    #undef LOAD_FEATS
}

// ---------------- fallback (ws >= ACC only): fp16 atomics, f32 feats -------
__global__ __launch_bounds__(256) void spconv_fp16acc_f32feats_kernel(
    const float*  __restrict__ feats_f32,
    const float*  __restrict__ weight,
    const int*    __restrict__ in_map,
    const int*    __restrict__ out_map,
    __half2*      __restrict__ accum)
{
    const int k    = blockIdx.y;
    const int wave = threadIdx.x >> 6;
    const int lane = threadIdx.x & 63;
    const int col  = lane & 15;
    const int quad = lane >> 4;
    const int tile = blockIdx.x * WPB + wave;
    if (tile >= TILES) return;
    const int m0 = tile * 16;
    const long long mapbase = (long long)k * MSGS;

    const int in_row = in_map[mapbase + m0 + col];
    int orow[4];
    #pragma unroll
    for (int i = 0; i < 4; ++i) orow[i] = out_map[mapbase + m0 + quad * 4 + i];

    const float* Wk = weight + k * (CIN * COUT);
    short8 bfr[2][2];
    #pragma unroll
    for (int s = 0; s < 2; ++s)
        #pragma unroll
        for (int t = 0; t < 2; ++t)
            #pragma unroll
            for (int j = 0; j < 8; ++j)
                bfr[s][t][j] = f2bf(Wk[(s * 32 + quad * 8 + j) * COUT + 2 * col + t]);

    const float* ar = feats_f32 + (long long)in_row * CIN + quad * 8;
    const float4* p0 = (const float4*)ar;
    const float4* p1 = (const float4*)(ar + 32);
    float4 l0 = p0[0], h0 = p0[1], l1 = p1[0], h1 = p1[1];
    short8 a0, a1;
    a0[0]=f2bf(l0.x); a0[1]=f2bf(l0.y); a0[2]=f2bf(l0.z); a0[3]=f2bf(l0.w);
    a0[4]=f2bf(h0.x); a0[5]=f2bf(h0.y); a0[6]=f2bf(h0.z); a0[7]=f2bf(h0.w);
    a1[0]=f2bf(l1.x); a1[1]=f2bf(l1.y); a1[2]=f2bf(l1.z); a1[3]=f2bf(l1.w);
    a1[4]=f2bf(h1.x); a1[5]=f2bf(h1.y); a1[6]=f2bf(h1.z); a1[7]=f2bf(h1.w);

    floatx4 acc0 = {0.f, 0.f, 0.f, 0.f};
    floatx4 acc1 = {0.f, 0.f, 0.f, 0.f};
    acc0 = __builtin_amdgcn_mfma_f32_16x16x32_bf16(a0, bfr[0][0], acc0, 0, 0, 0);
    acc1 = __builtin_amdgcn_mfma_f32_16x16x32_bf16(a0, bfr[0][1], acc1, 0, 0, 0);
    acc0 = __builtin_amdgcn_mfma_f32_16x16x32_bf16(a1, bfr[1][0], acc0, 0, 0, 0);
    acc1 = __builtin_amdgcn_mfma_f32_16x16x32_bf16(a1, bfr[1][1], acc1, 0, 0, 0);

    #pragma unroll
    for (int i = 0; i < 4; ++i) {
        __half2 h = __floats2half2_rn(acc0[i], acc1[i]);
        unsafeAtomicAdd(accum + (long long)orow[i] * 16 + col, h);
    }
}

// ---------------- last-resort fallback: f32 atomics to d_out ---------------
__global__ __launch_bounds__(256) void spconv_f32atomic_kernel(
    const float* __restrict__ feats,
    const float* __restrict__ weight,
    const int*   __restrict__ in_map,
    const int*   __restrict__ out_map,
    float*       __restrict__ out)
{
    const int k    = blockIdx.y;
    const int wave = threadIdx.x >> 6;
    const int lane = threadIdx.x & 63;
    const int col  = lane & 15;
    const int quad = lane >> 4;
    const int tile = blockIdx.x * WPB + wave;
    if (tile >= TILES) return;
    const int m0 = tile * 16;
    const long long mapbase = (long long)k * MSGS;

    const float* Wk = weight + k * (CIN * COUT);
    short8 bfr[2][2];
    #pragma unroll
    for (int s = 0; s < 2; ++s)
        #pragma unroll
        for (int t = 0; t < 2; ++t)
            #pragma unroll
            for (int j = 0; j < 8; ++j)
                bfr[s][t][j] = f2bf(Wk[(s * 32 + quad * 8 + j) * COUT + t * 16 + col]);

    const int in_row = in_map[mapbase + m0 + col];
    const float* arow = feats + (long long)in_row * CIN + quad * 8;

    floatx4 acc0 = {0.f, 0.f, 0.f, 0.f};
    floatx4 acc1 = {0.f, 0.f, 0.f, 0.f};
    #pragma unroll
    for (int s = 0; s < 2; ++s) {
        const float4* p = (const float4*)(arow + s * 32);
        float4 lo = p[0], hi = p[1];
        short8 a;
        a[0]=f2bf(lo.x); a[1]=f2bf(lo.y); a[2]=f2bf(lo.z); a[3]=f2bf(lo.w);
        a[4]=f2bf(hi.x); a[5]=f2bf(hi.y); a[6]=f2bf(hi.z); a[7]=f2bf(hi.w);
        acc0 = __builtin_amdgcn_mfma_f32_16x16x32_bf16(a, bfr[s][0], acc0, 0, 0, 0);
        acc1 = __builtin_amdgcn_mfma_f32_16x16x32_bf16(a, bfr[s][1], acc1, 0, 0, 0);
    }
    #pragma unroll
    for (int i = 0; i < 4; ++i) {
        const int orow = out_map[mapbase + m0 + quad * 4 + i];
        float* po = out + (long long)orow * COUT;
        atomicAdd(po + col,      acc0[i]);
        atomicAdd(po + col + 16, acc1[i]);
    }
}

// ---------------- fp16 accum -> f32 out ------------------------------------
__global__ __launch_bounds__(256) void h2_to_f32_kernel(
    const __half2* __restrict__ acc, float* __restrict__ out)
{
    const int t = blockIdx.x * blockDim.x + threadIdx.x;
    const __half2* p = acc + (size_t)t * 4;
    float2 f0 = __half22float2(p[0]);
    float2 f1 = __half22float2(p[1]);
    float2 f2 = __half22float2(p[2]);
    float2 f3 = __half22float2(p[3]);
    float4* o = (float4*)out + (size_t)t * 2;
    o[0] = make_float4(f0.x, f0.y, f1.x, f1.y);
    o[1] = make_float4(f2.x, f2.y, f3.x, f3.y);
}

extern "C" void kernel_launch(void* const* d_in, const int* in_sizes, int n_in,
                              void* d_out, int out_size, void* d_ws, size_t ws_size,
                              hipStream_t stream) {
    const float* feats   = (const float*)d_in[0];
    const float* weight  = (const float*)d_in[1];
    const int*   in_map  = (const int*)d_in[2];
    const int*   out_map = (const int*)d_in[3];
    float*       out     = (float*)d_out;

    if (ws_size >= ACC_BYTES + FEATS_BYTES) {
        __half2* accum    = (__half2*)d_ws;
        ushort*  feats_bf = (ushort*)((char*)d_ws + ACC_BYTES);

        prep_kernel<<<CVT_BLOCKS + ZERO_BLOCKS, 256, 0, stream>>>(
            feats, feats_bf, (float4*)accum);
        spconv_pipe_kernel<<<dim3(BLK_PER_K, KOFF), 256, 0, stream>>>(
            feats_bf, weight, in_map, out_map, accum);
        h2_to_f32_kernel<<<(NOUT * 16 / 4) / 256, 256, 0, stream>>>(accum, out);
    } else if (ws_size >= ACC_BYTES) {
        __half2* accum = (__half2*)d_ws;
        hipMemsetAsync(accum, 0, ACC_BYTES, stream);
        spconv_fp16acc_f32feats_kernel<<<dim3((TILES + WPB - 1) / WPB, KOFF), 256, 0, stream>>>(
            feats, weight, in_map, out_map, accum);
        h2_to_f32_kernel<<<(NOUT * 16 / 4) / 256, 256, 0, stream>>>(accum, out);
    } else {
        hipMemsetAsync(d_out, 0, (size_t)out_size * sizeof(float), stream);
        spconv_f32atomic_kernel<<<dim3((TILES + WPB - 1) / WPB, KOFF), 256, 0, stream>>>(
            feats, weight, in_map, out_map, out);
    }
}